// Round 24
// baseline (262.303 us; speedup 1.0000x reference)
//
#include <hip/hip_runtime.h>

// StochasticRegionalConvolution — fused MFMA conv
// (R21 schedule, 2 tiles/block with symmetric-pressure h0 prefetch).
// out[b,co,p,q] = coeff(p,q) * sum_{ci,kh,kw} x[b,ci,p+kh,q+kw] * W[co,ci,kh,kw]
//
// K1: coeff map (256x256 f32)                     -> d_ws[0, 256KB)
// K2: weight transform to MFMA A-frag order, bf16 -> d_ws[256KB, 328KB)
// K3: block = 16x32 region = 2 stacked 8x32 tiles. Per tile: R21's batched
//     staging + pure-LDS compute. Tile1's h0+af0 issued at tile0's mid-gap
//     (va/vc dead there -> peak regs unchanged), written after end-barrier;
//     epilogue slabs relocated to dead xs half-1 so targets are disjoint.
//     Tile1 pays no h0 stall; per-block fixed costs halved.

typedef short short8 __attribute__((ext_vector_type(8)));
typedef float floatx4 __attribute__((ext_vector_type(4)));
typedef unsigned int uint4v __attribute__((ext_vector_type(4)));

#define OUTR 62

__device__ inline unsigned f2bf_pack(float lo, float hi) {
    unsigned ul = __builtin_bit_cast(unsigned, lo);
    unsigned uh = __builtin_bit_cast(unsigned, hi);
    ul = (ul + 0x7FFFu + ((ul >> 16) & 1u)) >> 16;   // RNE
    uh = (uh + 0x7FFFu + ((uh >> 16) & 1u)) >> 16;
    return ul | (uh << 16);
}

__global__ void srconv_coeff_kernel(const int* __restrict__ h_idx,
                                    const int* __restrict__ w_idx,
                                    const float* __restrict__ lam,
                                    int T, float* __restrict__ coeff) {
    int p = blockIdx.x;
    int q = threadIdx.x;
    float c = 0.f;
    for (int t = 0; t < T; ++t) {
        int dh = p - h_idx[t];
        int dw = q - w_idx[t];
        if (dh >= 0 && dh < OUTR && dw >= 0 && dw < OUTR) c += lam[t];
    }
    coeff[(p << 8) + q] = c * (1.0f / 16.0f);
}

__global__ void srconv_wtrans_kernel(const float* __restrict__ wgt,
                                     uint4v* __restrict__ afrag) {
    int id = blockIdx.x * 256 + threadIdx.x;      // [0, 72*64)
    int l  = id & 63;
    int fi = id >> 6;                             // (kk*2+cb)*4 + m
    int m  = fi & 3;
    int cb = (fi >> 2) & 1;
    int kk = fi >> 3;
    int co  = m * 16 + (l & 15);
    int ci0 = cb * 32 + (l >> 4) * 8;
    float w[8];
#pragma unroll
    for (int j = 0; j < 8; ++j)
        w[j] = wgt[(co * 64 + ci0 + j) * 9 + kk];
    uint4v d;
    d.x = f2bf_pack(w[0], w[1]);
    d.y = f2bf_pack(w[2], w[3]);
    d.z = f2bf_pack(w[4], w[5]);
    d.w = f2bf_pack(w[6], w[7]);
    afrag[id] = d;
}

// LDS xs[half][pix 0..339][16 u32 ci-pairs], slot = cp ^ (((pix>>1)&3)<<2).
// B-frag (kg): b128 at slot16 = kg ^ ((pix>>1)&3) -> ci 8kg..8kg+7 in order.
// af_lds[kk*256 + m*64 + lane] (uint4v units): one cb-half's A-table, linear.
// Epilogue slabs overlay xs HALF-1 region (dead at epilogue time).
__launch_bounds__(256, 2)
__global__ void srconv_fused_kernel(const float* __restrict__ x,
                                    const float* __restrict__ coeff,
                                    const uint4v* __restrict__ afrag,
                                    float* __restrict__ out) {
    __shared__ __align__(16) unsigned xs[2 * 340 * 16];   // 43,520 B
    __shared__ __align__(16) uint4v af_lds[2304];         // 36,864 B

    const int tid  = threadIdx.x;
    const int lane = tid & 63;
    const int wv   = tid >> 6;            // 0..3 -> p-rows {2wv, 2wv+1}
    const int l15  = lane & 15;
    const int kg   = lane >> 4;

    // bijective XCD swizzle: 2048 blocks, 8 XCDs x 256 -> 2 batches per XCD
    const unsigned bid = blockIdx.x;
    const unsigned swz = (bid & 7) * 256 + (bid >> 3);
    const int b    = swz >> 7;            // 16 batches
    const int rest = swz & 127;           // 16 regions x 8 q-tiles
    const int R0   = (rest >> 3) << 4;    // region rows [R0, R0+16)
    const int Q0   = (rest & 7) << 5;

    // ---- region skip vote: 16x32 coeffs, 2 per thread ----
    float cm = 0.f;
#pragma unroll
    for (int i = 0; i < 2; ++i) {
        int u = i * 256 + tid;
        cm = fmaxf(cm, coeff[((R0 + (u >> 5)) << 8) + Q0 + (u & 31)]);
    }
    if (__syncthreads_count(cm != 0.f) == 0) {
        const floatx4 z = (floatx4){0.f, 0.f, 0.f, 0.f};
        for (int u = tid; u < 64 * 16 * 8; u += 256) {
            int q4 = u & 7;
            int pr = (u >> 3) & 15;
            int co = u >> 7;
            *(floatx4*)(out + (((b << 6) + co) << 16) +
                        ((R0 + pr) << 8) + Q0 + (q4 << 2)) = z;
        }
        return;
    }

    const float* xb = x + ((size_t)b << 22);

    floatx4 va[6][2], vb[6][2];
    uint4v  vc[9];

    // ---- staging helpers expressed inline per use (R21 decode) ----
#define ISSUE_A(CB)                                                         \
    _Pragma("unroll")                                                       \
    for (int i_ = 0; i_ < 9; ++i_) {                                        \
        int e_ = i_ * 256 + tid;                                            \
        vc[i_] = afrag[e_ + ((e_ >> 8) << 8) + ((CB) << 8)];                \
    }
#define WRITE_A()                                                           \
    _Pragma("unroll")                                                       \
    for (int i_ = 0; i_ < 9; ++i_) af_lds[i_ * 256 + tid] = vc[i_];
#define ISSUE_X(P0N, CB, V)                                                 \
    _Pragma("unroll")                                                       \
    for (int r_ = 0; r_ < 6; ++r_) {                                        \
        int u_  = r_ * 256 + tid;                                           \
        int uc_ = u_ < 1440 ? u_ : 1439;                                    \
        int cp_    = uc_ / 90;                                              \
        int rem_   = uc_ - cp_ * 90;                                        \
        int row_   = rem_ / 9;                                              \
        int chunk_ = rem_ - row_ * 9;                                       \
        int gr_    = min((P0N) + row_, 255);                                \
        int gcb_   = min(Q0 + (chunk_ << 2), 252);                          \
        const float* xp_ = xb + ((((CB) << 4) + cp_) << 17) +               \
                           (gr_ << 8) + gcb_;                               \
        V[r_][0] = *(const floatx4*)(xp_);                                  \
        V[r_][1] = *(const floatx4*)(xp_ + 65536);                          \
    }
#define WRITE_X(OFF, V)                                                     \
    _Pragma("unroll")                                                       \
    for (int r_ = 0; r_ < 6; ++r_) {                                        \
        int u_  = r_ * 256 + tid;                                           \
        int uc_ = u_ < 1440 ? u_ : 1439;                                    \
        int cp_    = uc_ / 90;                                              \
        int rem_   = uc_ - cp_ * 90;                                        \
        int row_   = rem_ / 9;                                              \
        int chunk_ = rem_ - row_ * 9;                                       \
        int c4_ = chunk_ << 2;                                              \
        _Pragma("unroll")                                                   \
        for (int j_ = 0; j_ < 4; ++j_) {                                    \
            if (u_ < 1440 && c4_ + j_ < 34) {                               \
                int pix_  = row_ * 34 + c4_ + j_;                           \
                int slot_ = cp_ ^ (((pix_ >> 1) & 3) << 2);                 \
                xs[(OFF) + (pix_ << 4) + slot_] =                           \
                    f2bf_pack(V[r_][0][j_], V[r_][1][j_]);                  \
            }                                                               \
        }                                                                   \
    }

    // ---- tile 0 prologue (R21 pattern) ----
    ISSUE_A(0);
    ISSUE_X(R0, 0, va);
    WRITE_A();
    WRITE_X(0, va);
    ISSUE_X(R0, 1, vb);
    ISSUE_A(1);
    __syncthreads();                      // B1: xs0 + af0 ready

    const int co_l = lane >> 3;
    const int q4   = lane & 7;

#pragma unroll
    for (int s = 0; s < 2; ++s) {
        const int P0  = R0 + (s << 3);
        const int prb = P0 + (wv << 1);

        float cf[2][2];
#pragma unroll
        for (int p = 0; p < 2; ++p)
#pragma unroll
            for (int h = 0; h < 2; ++h)
                cf[p][h] = coeff[((prb + p) << 8) + Q0 + (h << 4) + l15];

        floatx4 acc[4][2][2];
#pragma unroll
        for (int m = 0; m < 4; ++m)
#pragma unroll
            for (int p = 0; p < 2; ++p)
#pragma unroll
                for (int h = 0; h < 2; ++h)
                    acc[m][p][h] = (floatx4){0.f, 0.f, 0.f, 0.f};

        // ---- phases 0..8 (xs half 0 + af_lds) ----
#pragma unroll 2
        for (int t = 0; t < 9; ++t) {
            const int kh = t / 3;
            const int kw = t - kh * 3;
            short8 a[4];
#pragma unroll
            for (int m = 0; m < 4; ++m)
                a[m] = *reinterpret_cast<const short8*>(
                    &af_lds[(t << 8) + (m << 6) + lane]);
            short8 bf[2][2];
#pragma unroll
            for (int p = 0; p < 2; ++p)
#pragma unroll
                for (int h = 0; h < 2; ++h) {
                    int prl = (wv << 1) + p + kh;
                    int cl  = (h << 4) + l15 + kw;
                    int pix = prl * 34 + cl;
                    int off = (pix << 4) +
                              ((kg << 2) ^ (((pix >> 1) & 3) << 2));
                    bf[p][h] = *(const short8*)(&xs[off]);
                }
            __builtin_amdgcn_s_setprio(1);
#pragma unroll
            for (int m = 0; m < 4; ++m)
#pragma unroll
                for (int p = 0; p < 2; ++p)
#pragma unroll
                    for (int h = 0; h < 2; ++h)
                        acc[m][p][h] = __builtin_amdgcn_mfma_f32_16x16x32_bf16(
                            a[m], bf[p][h], acc[m][p][h], 0, 0, 0);
            __builtin_amdgcn_s_setprio(0);
        }
        __syncthreads();                  // B2: reads of xs0 + af_lds done

        // ---- mid gap: publish h1; prefetch next tile's h0 + af0 ----
        WRITE_X(5440, vb);                // vb -> xs half 1
        WRITE_A();                        // vc (af1) -> af_lds
        if (s == 0) {
            ISSUE_X(R0 + 8, 0, va);       // tile1 h0 -> flies 9-17 + epilogue
            ISSUE_A(0);                   // tile1 af0
        }
        __syncthreads();                  // B3: xs1 + af1 ready

        // ---- phases 9..17 (xs half 1 + af_lds) ----
#pragma unroll 2
        for (int t = 0; t < 9; ++t) {
            const int kh = t / 3;
            const int kw = t - kh * 3;
            short8 a[4];
#pragma unroll
            for (int m = 0; m < 4; ++m)
                a[m] = *reinterpret_cast<const short8*>(
                    &af_lds[(t << 8) + (m << 6) + lane]);
            short8 bf[2][2];
#pragma unroll
            for (int p = 0; p < 2; ++p)
#pragma unroll
                for (int h = 0; h < 2; ++h) {
                    int prl = (wv << 1) + p + kh;
                    int cl  = (h << 4) + l15 + kw;
                    int pix = prl * 34 + cl;
                    int off = 5440 + (pix << 4) +
                              ((kg << 2) ^ (((pix >> 1) & 3) << 2));
                    bf[p][h] = *(const short8*)(&xs[off]);
                }
            __builtin_amdgcn_s_setprio(1);
#pragma unroll
            for (int m = 0; m < 4; ++m)
#pragma unroll
                for (int p = 0; p < 2; ++p)
#pragma unroll
                    for (int h = 0; h < 2; ++h)
                        acc[m][p][h] = __builtin_amdgcn_mfma_f32_16x16x32_bf16(
                            a[m], bf[p][h], acc[m][p][h], 0, 0, 0);
            __builtin_amdgcn_s_setprio(0);
        }
        __syncthreads();                  // B4: reads of xs1 + af_lds done

        // ---- write next tile's h0 + af0 (targets disjoint from slabs) ----
        if (s == 0) {
            WRITE_X(0, va);               // tile1 h0 -> xs half 0
            WRITE_A();                    // af0 -> af_lds
        }

        // ---- epilogue: per-wave slabs in xs HALF-1 region (dead) ----
        // D layout (m89): col = lane&15 -> q, row = (lane>>4)*4+reg -> co16
        float* epb = reinterpret_cast<float*>(xs) + 5440;
#pragma unroll
        for (int p = 0; p < 2; ++p) {
            const int pr = prb + p;
#pragma unroll
            for (int m = 0; m < 4; ++m) {
                float* ep = epb + (((wv << 1) + (m & 1)) * 576);
#pragma unroll
                for (int h = 0; h < 2; ++h)
#pragma unroll
                    for (int reg = 0; reg < 4; ++reg)
                        ep[((kg << 2) + reg) * 36 + (h << 4) + l15] =
                            acc[m][p][h][reg] * cf[p][h];
                // wave-internal RAW through LDS: compiler lgkmcnt orders
#pragma unroll
                for (int j = 0; j < 2; ++j) {
                    const floatx4 v = *reinterpret_cast<const floatx4*>(
                        &ep[(co_l + (j << 3)) * 36 + (q4 << 2)]);
                    const int co = (m << 4) + co_l + (j << 3);
                    *(floatx4*)(out + (((b << 6) + co) << 16) +
                                (pr << 8) + Q0 + (q4 << 2)) = v;
                }
            }
        }

        if (s == 0) {
            ISSUE_X(R0 + 8, 1, vb);       // tile1 h1 -> flies tile1 phases 0-8
            ISSUE_A(1);                   // tile1 af1
            __syncthreads();              // B5: xs0 + af0 ready for tile 1
        }
    }
#undef ISSUE_A
#undef WRITE_A
#undef ISSUE_X
#undef WRITE_X
}

extern "C" void kernel_launch(void* const* d_in, const int* in_sizes, int n_in,
                              void* d_out, int out_size, void* d_ws, size_t ws_size,
                              hipStream_t stream) {
    const float* x     = (const float*)d_in[0];
    const float* wgt   = (const float*)d_in[1];
    const int*   h_idx = (const int*)d_in[2];
    const int*   w_idx = (const int*)d_in[3];
    const float* lam   = (const float*)d_in[4];
    float*       out   = (float*)d_out;
    float*       coeff = (float*)d_ws;                        // 256 KB
    char*        af_b  = (char*)d_ws + 65536 * sizeof(float); // 72 KB
    const int    T     = in_sizes[2];

    srconv_coeff_kernel<<<256, 256, 0, stream>>>(h_idx, w_idx, lam, T, coeff);
    srconv_wtrans_kernel<<<18, 256, 0, stream>>>(wgt, (uint4v*)af_b);
    // 2048 blocks = (16 regions x 8 q-tiles) x 16 batches, XCD-swizzled
    srconv_fused_kernel<<<2048, 256, 0, stream>>>(
        x, coeff, (const uint4v*)af_b, out);
}

// Round 25
// 167.065 us; speedup vs baseline: 1.5701x; 1.5701x over previous
//
#include <hip/hip_runtime.h>

// StochasticRegionalConvolution — fused MFMA conv (champion, R21/R23 final).
// out[b,co,p,q] = coeff(p,q) * sum_{ci,kh,kw} x[b,ci,p+kh,q+kw] * W[co,ci,kh,kw]
//
// K1: coeff map (256x256 f32)                     -> d_ws[0, 256KB)
// K2: weight transform to MFMA A-frag order, bf16 -> d_ws[256KB, 328KB)
// K3: fused conv: 8x32 pixel tile, 256 thr / 4 waves. Batched staging:
//     ISSUE af0+va -> WRITE af0,va (waits those only) -> ISSUE vb+af1 ->
//     barrier -> phases 0-8 (pure LDS+MFMA; vb/af1 fly) -> barrier ->
//     WRITE vb,af1 -> barrier -> phases 9-17 -> epilogue.

typedef short short8 __attribute__((ext_vector_type(8)));
typedef float floatx4 __attribute__((ext_vector_type(4)));
typedef unsigned int uint4v __attribute__((ext_vector_type(4)));

#define OUTR 62

__device__ inline unsigned f2bf_pack(float lo, float hi) {
    unsigned ul = __builtin_bit_cast(unsigned, lo);
    unsigned uh = __builtin_bit_cast(unsigned, hi);
    ul = (ul + 0x7FFFu + ((ul >> 16) & 1u)) >> 16;   // RNE
    uh = (uh + 0x7FFFu + ((uh >> 16) & 1u)) >> 16;
    return ul | (uh << 16);
}

__global__ void srconv_coeff_kernel(const int* __restrict__ h_idx,
                                    const int* __restrict__ w_idx,
                                    const float* __restrict__ lam,
                                    int T, float* __restrict__ coeff) {
    int p = blockIdx.x;
    int q = threadIdx.x;
    float c = 0.f;
    for (int t = 0; t < T; ++t) {
        int dh = p - h_idx[t];
        int dw = q - w_idx[t];
        if (dh >= 0 && dh < OUTR && dw >= 0 && dw < OUTR) c += lam[t];
    }
    coeff[(p << 8) + q] = c * (1.0f / 16.0f);
}

__global__ void srconv_wtrans_kernel(const float* __restrict__ wgt,
                                     uint4v* __restrict__ afrag) {
    int id = blockIdx.x * 256 + threadIdx.x;      // [0, 72*64)
    int l  = id & 63;
    int fi = id >> 6;                             // (kk*2+cb)*4 + m
    int m  = fi & 3;
    int cb = (fi >> 2) & 1;
    int kk = fi >> 3;
    int co  = m * 16 + (l & 15);
    int ci0 = cb * 32 + (l >> 4) * 8;
    float w[8];
#pragma unroll
    for (int j = 0; j < 8; ++j)
        w[j] = wgt[(co * 64 + ci0 + j) * 9 + kk];
    uint4v d;
    d.x = f2bf_pack(w[0], w[1]);
    d.y = f2bf_pack(w[2], w[3]);
    d.z = f2bf_pack(w[4], w[5]);
    d.w = f2bf_pack(w[6], w[7]);
    afrag[id] = d;
}

// LDS xs[cb][pix 0..339][16 u32 ci-pairs], slot = cp ^ (((pix>>1)&3)<<2).
// B-frag (kg): b128 at slot16 = kg ^ ((pix>>1)&3) -> ci 8kg..8kg+7 in order.
// af_lds[kk*256 + m*64 + lane] (uint4v units): one cb-half's A-table, linear.
__launch_bounds__(256, 2)
__global__ void srconv_fused_kernel(const float* __restrict__ x,
                                    const float* __restrict__ coeff,
                                    const uint4v* __restrict__ afrag,
                                    float* __restrict__ out) {
    __shared__ __align__(16) unsigned xs[2 * 340 * 16];   // 43,520 B
    __shared__ __align__(16) uint4v af_lds[2304];         // 36,864 B

    const int tid  = threadIdx.x;
    const int lane = tid & 63;
    const int wv   = tid >> 6;            // 0..3 -> p-rows {2wv, 2wv+1}
    const int l15  = lane & 15;
    const int kg   = lane >> 4;

    // bijective XCD swizzle: 4096 blocks, 8 XCDs x 512 -> 2 batches per XCD
    const unsigned bid = blockIdx.x;
    const unsigned swz = (bid & 7) * 512 + (bid >> 3);
    const int b    = swz >> 8;
    const int tile = swz & 255;           // 32 p-tiles x 8 q-tiles
    const int P0   = (tile >> 3) << 3;
    const int Q0   = (tile & 7) << 5;

    // ---- tile skip vote ----
    float myc = coeff[((P0 + (tid >> 5)) << 8) + Q0 + (tid & 31)];
    if (__syncthreads_count(myc != 0.f) == 0) {
        const floatx4 z = (floatx4){0.f, 0.f, 0.f, 0.f};
        for (int u = tid; u < 64 * 8 * 8; u += 256) {
            int q4 = u & 7;
            int pr = (u >> 3) & 7;
            int co = u >> 6;
            *(floatx4*)(out + (((b << 6) + co) << 16) +
                        ((P0 + pr) << 8) + Q0 + (q4 << 2)) = z;
        }
        return;
    }

    const int prb = P0 + (wv << 1);

    // ---- hoisted epilogue coeff loads ----
    float cf[2][2];
#pragma unroll
    for (int p = 0; p < 2; ++p)
#pragma unroll
        for (int h = 0; h < 2; ++h)
            cf[p][h] = coeff[((prb + p) << 8) + Q0 + (h << 4) + l15];

    const float* xb = x + ((size_t)b << 22);

    // ---- staging. x half: 1440 tasks = 16 cp x 10 rows x 9 chunks.
    // A half: 2304 uint4v; element e of half cb sits at global
    //   g = e + (e>>8)*256 + cb*256   (kk = e>>8).
    floatx4 va[6][2], vb[6][2];
    uint4v  vc[9];                        // A-table regs (reused af0 then af1)

#pragma unroll
    for (int i = 0; i < 9; ++i) {         // ISSUE A half 0
        int e = i * 256 + tid;
        vc[i] = afrag[e + ((e >> 8) << 8)];
    }
#pragma unroll
    for (int r = 0; r < 6; ++r) {         // ISSUE x half 0
        int u  = r * 256 + tid;
        int uc = u < 1440 ? u : 1439;
        int cp    = uc / 90;
        int rem   = uc - cp * 90;
        int row   = rem / 9;
        int chunk = rem - row * 9;
        int gr    = min(P0 + row, 255);
        int gcb   = min(Q0 + (chunk << 2), 252);
        const float* xp = xb + (cp << 17) + (gr << 8) + gcb;
        va[r][0] = *(const floatx4*)(xp);
        va[r][1] = *(const floatx4*)(xp + 65536);
    }

#pragma unroll
    for (int i = 0; i < 9; ++i)           // WRITE A half 0 (waits af0 region)
        af_lds[i * 256 + tid] = vc[i];
#pragma unroll
    for (int r = 0; r < 6; ++r) {         // WRITE x half 0 (waits va)
        int u  = r * 256 + tid;
        int uc = u < 1440 ? u : 1439;
        int cp    = uc / 90;
        int rem   = uc - cp * 90;
        int row   = rem / 9;
        int chunk = rem - row * 9;
        int c4 = chunk << 2;
#pragma unroll
        for (int j = 0; j < 4; ++j) {
            if (u < 1440 && c4 + j < 34) {
                int pix = row * 34 + c4 + j;
                int slot = cp ^ (((pix >> 1) & 3) << 2);
                xs[(pix << 4) + slot] = f2bf_pack(va[r][0][j], va[r][1][j]);
            }
        }
    }

#pragma unroll
    for (int r = 0; r < 6; ++r) {         // ISSUE x half 1 (flies over phases 0-8)
        int u  = r * 256 + tid;
        int uc = u < 1440 ? u : 1439;
        int cp    = uc / 90;
        int rem   = uc - cp * 90;
        int row   = rem / 9;
        int chunk = rem - row * 9;
        int gr    = min(P0 + row, 255);
        int gcb   = min(Q0 + (chunk << 2), 252);
        const float* xp = xb + ((16 + cp) << 17) + (gr << 8) + gcb;
        vb[r][0] = *(const floatx4*)(xp);
        vb[r][1] = *(const floatx4*)(xp + 65536);
    }
#pragma unroll
    for (int i = 0; i < 9; ++i) {         // ISSUE A half 1 (flies too)
        int e = i * 256 + tid;
        vc[i] = afrag[e + ((e >> 8) << 8) + 256];
    }
    __syncthreads();                      // half-0 (x + A) ready

    floatx4 acc[4][2][2];                 // [m: co16][p: row][h: q-half]
#pragma unroll
    for (int m = 0; m < 4; ++m)
#pragma unroll
        for (int p = 0; p < 2; ++p)
#pragma unroll
            for (int h = 0; h < 2; ++h)
                acc[m][p][h] = (floatx4){0.f, 0.f, 0.f, 0.f};

    // ---- phases 0..8 (cb = 0): pure LDS + MFMA ----
#pragma unroll 2
    for (int t = 0; t < 9; ++t) {
        const int kh = t / 3;
        const int kw = t - kh * 3;

        short8 a[4];
#pragma unroll
        for (int m = 0; m < 4; ++m)
            a[m] = *reinterpret_cast<const short8*>(
                &af_lds[(t << 8) + (m << 6) + lane]);
        short8 bf[2][2];
#pragma unroll
        for (int p = 0; p < 2; ++p)
#pragma unroll
            for (int h = 0; h < 2; ++h) {
                int prl = (wv << 1) + p + kh;          // 0..9
                int cl  = (h << 4) + l15 + kw;         // 0..33
                int pix = prl * 34 + cl;
                int off = (pix << 4) +
                          ((kg << 2) ^ (((pix >> 1) & 3) << 2));
                bf[p][h] = *(const short8*)(&xs[off]);
            }
        __builtin_amdgcn_s_setprio(1);
#pragma unroll
        for (int m = 0; m < 4; ++m)
#pragma unroll
            for (int p = 0; p < 2; ++p)
#pragma unroll
                for (int h = 0; h < 2; ++h)
                    acc[m][p][h] = __builtin_amdgcn_mfma_f32_16x16x32_bf16(
                        a[m], bf[p][h], acc[m][p][h], 0, 0, 0);
        __builtin_amdgcn_s_setprio(0);
    }
    __syncthreads();                      // WAR: all reads of af_lds/xs0 done

    // ---- WRITE x half 1 + A half 1 ----
#pragma unroll
    for (int r = 0; r < 6; ++r) {
        int u  = r * 256 + tid;
        int uc = u < 1440 ? u : 1439;
        int cp    = uc / 90;
        int rem   = uc - cp * 90;
        int row   = rem / 9;
        int chunk = rem - row * 9;
        int c4 = chunk << 2;
#pragma unroll
        for (int j = 0; j < 4; ++j) {
            if (u < 1440 && c4 + j < 34) {
                int pix = row * 34 + c4 + j;
                int slot = cp ^ (((pix >> 1) & 3) << 2);
                xs[5440 + (pix << 4) + slot] =
                    f2bf_pack(vb[r][0][j], vb[r][1][j]);
            }
        }
    }
#pragma unroll
    for (int i = 0; i < 9; ++i)
        af_lds[i * 256 + tid] = vc[i];
    __syncthreads();                      // half-1 (x + A) ready

    // ---- phases 9..17 (cb = 1): pure LDS + MFMA ----
#pragma unroll 2
    for (int t = 0; t < 9; ++t) {
        const int kh = t / 3;
        const int kw = t - kh * 3;

        short8 a[4];
#pragma unroll
        for (int m = 0; m < 4; ++m)
            a[m] = *reinterpret_cast<const short8*>(
                &af_lds[(t << 8) + (m << 6) + lane]);
        short8 bf[2][2];
#pragma unroll
        for (int p = 0; p < 2; ++p)
#pragma unroll
            for (int h = 0; h < 2; ++h) {
                int prl = (wv << 1) + p + kh;
                int cl  = (h << 4) + l15 + kw;
                int pix = prl * 34 + cl;
                int off = 5440 + (pix << 4) +
                          ((kg << 2) ^ (((pix >> 1) & 3) << 2));
                bf[p][h] = *(const short8*)(&xs[off]);
            }
        __builtin_amdgcn_s_setprio(1);
#pragma unroll
        for (int m = 0; m < 4; ++m)
#pragma unroll
            for (int p = 0; p < 2; ++p)
#pragma unroll
                for (int h = 0; h < 2; ++h)
                    acc[m][p][h] = __builtin_amdgcn_mfma_f32_16x16x32_bf16(
                        a[m], bf[p][h], acc[m][p][h], 0, 0, 0);
        __builtin_amdgcn_s_setprio(0);
    }
    __syncthreads();                      // all waves done reading xs

    // ---- epilogue: per-wave ping-pong slabs overlaid on xs, no barriers ----
    // D layout (m89): col = lane&15 -> q, row = (lane>>4)*4+reg -> co-within-16
    float* epb = reinterpret_cast<float*>(xs);
    const int co_l = lane >> 3;           // 0..7
    const int q4   = lane & 7;

#pragma unroll
    for (int p = 0; p < 2; ++p) {
        const int pr = prb + p;
#pragma unroll
        for (int m = 0; m < 4; ++m) {
            float* ep = epb + (((wv << 1) + (m & 1)) * 576);
#pragma unroll
            for (int h = 0; h < 2; ++h)
#pragma unroll
                for (int reg = 0; reg < 4; ++reg)
                    ep[((kg << 2) + reg) * 36 + (h << 4) + l15] =
                        acc[m][p][h][reg] * cf[p][h];
            // wave-internal RAW through LDS: compiler-inserted lgkmcnt orders
#pragma unroll
            for (int j = 0; j < 2; ++j) {
                const floatx4 v = *reinterpret_cast<const floatx4*>(
                    &ep[(co_l + (j << 3)) * 36 + (q4 << 2)]);
                const int co = (m << 4) + co_l + (j << 3);
                *(floatx4*)(out + (((b << 6) + co) << 16) +
                            (pr << 8) + Q0 + (q4 << 2)) = v;
            }
        }
    }
}

extern "C" void kernel_launch(void* const* d_in, const int* in_sizes, int n_in,
                              void* d_out, int out_size, void* d_ws, size_t ws_size,
                              hipStream_t stream) {
    const float* x     = (const float*)d_in[0];
    const float* wgt   = (const float*)d_in[1];
    const int*   h_idx = (const int*)d_in[2];
    const int*   w_idx = (const int*)d_in[3];
    const float* lam   = (const float*)d_in[4];
    float*       out   = (float*)d_out;
    float*       coeff = (float*)d_ws;                        // 256 KB
    char*        af_b  = (char*)d_ws + 65536 * sizeof(float); // 72 KB
    const int    T     = in_sizes[2];

    srconv_coeff_kernel<<<256, 256, 0, stream>>>(h_idx, w_idx, lam, T, coeff);
    srconv_wtrans_kernel<<<18, 256, 0, stream>>>(wgt, (uint4v*)af_b);
    // 4096 blocks = (32 p-tiles x 8 q-tiles) x 16 batches, XCD-swizzled
    srconv_fused_kernel<<<4096, 256, 0, stream>>>(
        x, coeff, (const uint4v*)af_b, out);
}